// Round 5
// baseline (259.761 us; speedup 1.0000x reference)
//
#include <hip/hip_runtime.h>

// MultiKR rec-path, fused, FP32.  v5: LDS-pipe-debt reduction.
// Law: one act ds_read_b128 feeds 4*C fmacs (C = cols per lane). R4 had C=1..2
// -> LDS-bound. v5: C=4 for h1/h2 (weights streamed from GLOBAL via VMEM pipe,
// coalesced float4, depth-1 prefetch as in R4), C=2 for uMLP (weights from LDS
// b64). 32 samples/block, 256 thr (4 waves), grid 512 -> 2 blocks/CU (54 KB LDS).
// Acts transposed in LDS [dim][sample], PAD=36 (bank (4d+s)%32, b128-aligned).

constexpr int BTOT = 16384;
constexpr int SPB  = 32;
constexpr int PAD  = 36;

__global__ __launch_bounds__(256, 2) void multikr_fused(
    const int* __restrict__ user_id, const int* __restrict__ item_id,
    const float* __restrict__ rec_target,
    const float* __restrict__ user_emb, const float* __restrict__ item_emb,
    const float* __restrict__ entity_emb,
    const float* __restrict__ w_vv, const float* __restrict__ w_ev,
    const float* __restrict__ w_ve, const float* __restrict__ w_ee,
    const float* __restrict__ b_v, const float* __restrict__ b_e,
    const float* __restrict__ Wul, const float* __restrict__ bul,
    const float* __restrict__ W1, const float* __restrict__ b1,
    const float* __restrict__ W2, const float* __restrict__ b2,
    const float* __restrict__ W3, const float* __restrict__ b3,
    float* __restrict__ out)
{
    // rows 0..63: user | 64..127: item | 128..191: head -> h1[0:64) | 192..255: user' -> h1[64:128)
    __shared__ __align__(16) float sm[256 * PAD];   // 36.9 KB
    __shared__ __align__(16) float sWul[64 * 64];   // 16 KB
    __shared__ __align__(16) float scal[4][SPB];    // 0.5 KB

    const int t    = threadIdx.x;
    const int lane = t & 63;
    const int wv   = t >> 6;             // wave 0..3 owns samples [8wv, 8wv+8)
    const int s0   = blockIdx.x * SPB;

    float* U  = sm;                      // rows 0..63
    float* IT = sm + 64 * PAD;           // rows 64..127
    float* HD = sm + 128 * PAD;          // rows 128..191
    float* SP = sm + 192 * PAD;          // rows 192..255

    const int dh   = lane >> 5;          // d-half for dots / out
    const int sdot = lane & 31;

    // per-wave cross-weight vector slice -> regs (wave wv owns dot #wv)
    float wcr[32];
    {
        const float* wsrc = (wv == 0) ? w_vv : (wv == 1) ? w_ev : (wv == 2) ? w_ve : w_ee;
#pragma unroll
        for (int q = 0; q < 8; ++q) {
            const float4 w4 = *(const float4*)(wsrc + 32 * dh + 4 * q);
            wcr[4*q] = w4.x; wcr[4*q+1] = w4.y; wcr[4*q+2] = w4.z; wcr[4*q+3] = w4.w;
        }
    }

    // ---------------- gather + stage -----------------------------------------
    {
        const int s = t & 31, p = t >> 5;            // p 0..7 -> dims [8p, 8p+8)
        const int uid = user_id[s0 + s], iid = item_id[s0 + s];
        const float4* ur = (const float4*)(user_emb   + (size_t)uid * 64 + 8 * p);
        const float4* ir = (const float4*)(item_emb   + (size_t)iid * 64 + 8 * p);
        const float4* er = (const float4*)(entity_emb + (size_t)iid * 64 + 8 * p);
        const float4 u0 = ur[0], u1 = ur[1];
        const float4 i0 = ir[0], i1 = ir[1];
        const float4 e0 = er[0], e1 = er[1];
        const int db = 8 * p;
        U [(db+0)*PAD+s]=u0.x; U [(db+1)*PAD+s]=u0.y; U [(db+2)*PAD+s]=u0.z; U [(db+3)*PAD+s]=u0.w;
        U [(db+4)*PAD+s]=u1.x; U [(db+5)*PAD+s]=u1.y; U [(db+6)*PAD+s]=u1.z; U [(db+7)*PAD+s]=u1.w;
        IT[(db+0)*PAD+s]=i0.x; IT[(db+1)*PAD+s]=i0.y; IT[(db+2)*PAD+s]=i0.z; IT[(db+3)*PAD+s]=i0.w;
        IT[(db+4)*PAD+s]=i1.x; IT[(db+5)*PAD+s]=i1.y; IT[(db+6)*PAD+s]=i1.z; IT[(db+7)*PAD+s]=i1.w;
        HD[(db+0)*PAD+s]=e0.x; HD[(db+1)*PAD+s]=e0.y; HD[(db+2)*PAD+s]=e0.z; HD[(db+3)*PAD+s]=e0.w;
        HD[(db+4)*PAD+s]=e1.x; HD[(db+5)*PAD+s]=e1.y; HD[(db+6)*PAD+s]=e1.z; HD[(db+7)*PAD+s]=e1.w;
        const float4* wg = (const float4*)Wul;
        float4*       ws = (float4*)sWul;
#pragma unroll
        for (int i = 0; i < 4; ++i) ws[i * 256 + t] = wg[i * 256 + t];
    }
    __syncthreads();
    const float bv = b_v[0], be = b_e[0];

    // ---------------- 2 x { user MLP + cross dots ; cross update } -----------
    {
        const int cg = lane & 31;                    // cols {2cg, 2cg+1}
        const int m0 = 8 * wv + 4 * (lane >> 5);     // 4-sample group
#pragma unroll
        for (int layer = 0; layer < 2; ++layer) {
            const float* ub = (layer == 0) ? U : SP;
            float*       vb = (layer == 0) ? SP : U;
            {   // user' : C=2 cols x S=4 samples per lane
                const float2 bb = *(const float2*)(bul + 2 * cg);
                float a0[4] = {bb.x, bb.x, bb.x, bb.x};
                float a1[4] = {bb.y, bb.y, bb.y, bb.y};
#pragma unroll
                for (int d = 0; d < 64; ++d) {
                    const float4 av = *(const float4*)(ub + d * PAD + m0);
                    const float2 w  = *(const float2*)(sWul + d * 64 + 2 * cg);
                    a0[0]=fmaf(av.x,w.x,a0[0]); a0[1]=fmaf(av.y,w.x,a0[1]);
                    a0[2]=fmaf(av.z,w.x,a0[2]); a0[3]=fmaf(av.w,w.x,a0[3]);
                    a1[0]=fmaf(av.x,w.y,a1[0]); a1[1]=fmaf(av.y,w.y,a1[1]);
                    a1[2]=fmaf(av.z,w.y,a1[2]); a1[3]=fmaf(av.w,w.y,a1[3]);
                }
                *(float4*)(vb + (2*cg    ) * PAD + m0) =
                    make_float4(fmaxf(a0[0],0.f),fmaxf(a0[1],0.f),fmaxf(a0[2],0.f),fmaxf(a0[3],0.f));
                *(float4*)(vb + (2*cg + 1) * PAD + m0) =
                    make_float4(fmaxf(a1[0],0.f),fmaxf(a1[1],0.f),fmaxf(a1[2],0.f),fmaxf(a1[3],0.f));
            }
            {   // dots: wave wv -> scal[wv]; lane-halves split d
                const float* src = (wv & 1) ? IT : HD;
                float a = 0.f;
#pragma unroll
                for (int k = 0; k < 32; ++k)
                    a = fmaf(src[(32 * dh + k) * PAD + sdot], wcr[k], a);
                a += __shfl_xor(a, 32);
                if (dh == 0) scal[wv][sdot] = a;
            }
            __syncthreads();
            {   // update: d = lane, wave wv -> samples [8wv, 8wv+8)
                float* ip = IT + lane * PAD + 8 * wv;
                float* hp = HD + lane * PAD + 8 * wv;
                const float4 iv0 = *(const float4*)(ip),     iv1 = *(const float4*)(ip + 4);
                const float4 hv0 = *(const float4*)(hp),     hv1 = *(const float4*)(hp + 4);
                const float4 sa0 = *(const float4*)&scal[0][8*wv], sa1 = *(const float4*)&scal[0][8*wv+4];
                const float4 sb0 = *(const float4*)&scal[1][8*wv], sb1 = *(const float4*)&scal[1][8*wv+4];
                *(float4*)(ip) = make_float4(
                    fmaf(iv0.x, sa0.x, fmaf(hv0.x, sb0.x, bv)),
                    fmaf(iv0.y, sa0.y, fmaf(hv0.y, sb0.y, bv)),
                    fmaf(iv0.z, sa0.z, fmaf(hv0.z, sb0.z, bv)),
                    fmaf(iv0.w, sa0.w, fmaf(hv0.w, sb0.w, bv)));
                *(float4*)(ip + 4) = make_float4(
                    fmaf(iv1.x, sa1.x, fmaf(hv1.x, sb1.x, bv)),
                    fmaf(iv1.y, sa1.y, fmaf(hv1.y, sb1.y, bv)),
                    fmaf(iv1.z, sa1.z, fmaf(hv1.z, sb1.z, bv)),
                    fmaf(iv1.w, sa1.w, fmaf(hv1.w, sb1.w, bv)));
                if (layer == 0) {
                    const float4 sc0 = *(const float4*)&scal[2][8*wv], sc1 = *(const float4*)&scal[2][8*wv+4];
                    const float4 sd0 = *(const float4*)&scal[3][8*wv], sd1 = *(const float4*)&scal[3][8*wv+4];
                    *(float4*)(hp) = make_float4(
                        fmaf(iv0.x, sc0.x, fmaf(hv0.x, sd0.x, be)),
                        fmaf(iv0.y, sc0.y, fmaf(hv0.y, sd0.y, be)),
                        fmaf(iv0.z, sc0.z, fmaf(hv0.z, sd0.z, be)),
                        fmaf(iv0.w, sc0.w, fmaf(hv0.w, sd0.w, be)));
                    *(float4*)(hp + 4) = make_float4(
                        fmaf(iv1.x, sc1.x, fmaf(hv1.x, sd1.x, be)),
                        fmaf(iv1.y, sc1.y, fmaf(hv1.y, sd1.y, be)),
                        fmaf(iv1.z, sc1.z, fmaf(hv1.z, sd1.z, be)),
                        fmaf(iv1.w, sc1.w, fmaf(hv1.w, sd1.w, be)));
                }
            }
            __syncthreads();
        }
    }
    // user final rows 0..63, item final rows 64..127.

    // ---------------- h1 = relu([user|item] @ W1 + b1): C=4 cols/lane ---------
    {
        const int c0  = 4 * (lane & 31);             // cols [c0, c0+4)
        const int m0h = 8 * wv + 4 * (lane >> 5);    // 4-sample group
        float acc[4][4];
        const float4 bb = *(const float4*)(b1 + c0);
#pragma unroll
        for (int i = 0; i < 4; ++i) { acc[0][i]=bb.x; acc[1][i]=bb.y; acc[2][i]=bb.z; acc[3][i]=bb.w; }
        float4 wA[8], wB[8];
        auto ldg = [&](float4* buf, int db) {
#pragma unroll
            for (int k = 0; k < 8; ++k) buf[k] = *(const float4*)(W1 + (db + k) * 128 + c0);
        };
        auto cmp = [&](const float4* buf, int db) {
#pragma unroll
            for (int k = 0; k < 8; ++k) {
                const float4 av = *(const float4*)(sm + (db + k) * PAD + m0h);
                const float4 w  = buf[k];
                acc[0][0]=fmaf(av.x,w.x,acc[0][0]); acc[0][1]=fmaf(av.y,w.x,acc[0][1]);
                acc[0][2]=fmaf(av.z,w.x,acc[0][2]); acc[0][3]=fmaf(av.w,w.x,acc[0][3]);
                acc[1][0]=fmaf(av.x,w.y,acc[1][0]); acc[1][1]=fmaf(av.y,w.y,acc[1][1]);
                acc[1][2]=fmaf(av.z,w.y,acc[1][2]); acc[1][3]=fmaf(av.w,w.y,acc[1][3]);
                acc[2][0]=fmaf(av.x,w.z,acc[2][0]); acc[2][1]=fmaf(av.y,w.z,acc[2][1]);
                acc[2][2]=fmaf(av.z,w.z,acc[2][2]); acc[2][3]=fmaf(av.w,w.z,acc[2][3]);
                acc[3][0]=fmaf(av.x,w.w,acc[3][0]); acc[3][1]=fmaf(av.y,w.w,acc[3][1]);
                acc[3][2]=fmaf(av.z,w.w,acc[3][2]); acc[3][3]=fmaf(av.w,w.w,acc[3][3]);
            }
        };
        ldg(wA, 0);
#pragma unroll
        for (int g = 0; g < 8; ++g) {                // 16 groups of 8 d over [0,128)
            ldg(wB, 16 * g + 8);
            cmp(wA, 16 * g);
            if (g < 7) ldg(wA, 16 * g + 16);
            cmp(wB, 16 * g + 8);
        }
#pragma unroll
        for (int c = 0; c < 4; ++c)                  // h1 col (c0+c) -> row 128+c0+c
            *(float4*)(sm + (128 + c0 + c) * PAD + m0h) =
                make_float4(fmaxf(acc[c][0],0.f),fmaxf(acc[c][1],0.f),
                            fmaxf(acc[c][2],0.f),fmaxf(acc[c][3],0.f));
    }
    __syncthreads();

    // ---------------- h2 = relu(h1 @ W2 + b2): C=4 cols/lane, S=2 ------------
    {
        const int c0 = 4 * (lane & 15);              // cols [c0, c0+4)
        const int m2 = 8 * wv + 2 * (lane >> 4);     // 2-sample group
        float acc[4][2];
        const float4 bb = *(const float4*)(b2 + c0);
        acc[0][0]=acc[0][1]=bb.x; acc[1][0]=acc[1][1]=bb.y;
        acc[2][0]=acc[2][1]=bb.z; acc[3][0]=acc[3][1]=bb.w;
        float4 wA[8], wB[8];
        auto ldg = [&](float4* buf, int db) {
#pragma unroll
            for (int k = 0; k < 8; ++k) buf[k] = *(const float4*)(W2 + (db + k) * 64 + c0);
        };
        auto cmp = [&](const float4* buf, int db) {
#pragma unroll
            for (int k = 0; k < 8; ++k) {
                const float2 av = *(const float2*)(sm + (128 + db + k) * PAD + m2);
                const float4 w  = buf[k];
                acc[0][0]=fmaf(av.x,w.x,acc[0][0]); acc[0][1]=fmaf(av.y,w.x,acc[0][1]);
                acc[1][0]=fmaf(av.x,w.y,acc[1][0]); acc[1][1]=fmaf(av.y,w.y,acc[1][1]);
                acc[2][0]=fmaf(av.x,w.z,acc[2][0]); acc[2][1]=fmaf(av.y,w.z,acc[2][1]);
                acc[3][0]=fmaf(av.x,w.w,acc[3][0]); acc[3][1]=fmaf(av.y,w.w,acc[3][1]);
            }
        };
        ldg(wA, 0);
#pragma unroll
        for (int g = 0; g < 8; ++g) {                // 16 groups of 8 d over [0,128)
            ldg(wB, 16 * g + 8);
            cmp(wA, 16 * g);
            if (g < 7) ldg(wA, 16 * g + 16);
            cmp(wB, 16 * g + 8);
        }
#pragma unroll
        for (int c = 0; c < 4; ++c)                  // h2 col (c0+c) -> row c0+c
            *(float2*)(sm + (c0 + c) * PAD + m2) =
                make_float2(fmaxf(acc[c][0],0.f), fmaxf(acc[c][1],0.f));
    }
    __syncthreads();

    // ---------------- out = relu(h2 @ W3 + b3) + rec_target -------------------
    if (wv == 0) {
        float w3r[32];
#pragma unroll
        for (int q = 0; q < 8; ++q) {
            const float4 w4 = *(const float4*)(W3 + 32 * dh + 4 * q);
            w3r[4*q] = w4.x; w3r[4*q+1] = w4.y; w3r[4*q+2] = w4.z; w3r[4*q+3] = w4.w;
        }
        float a = 0.f;
#pragma unroll
        for (int k = 0; k < 32; ++k)
            a = fmaf(sm[(32 * dh + k) * PAD + sdot], w3r[k], a);
        a += __shfl_xor(a, 32);
        if (dh == 0) out[s0 + sdot] = fmaxf(a + b3[0], 0.f);
    } else if (wv == 1) {
        if (lane < 32) out[BTOT + s0 + lane] = rec_target[s0 + lane];
    }
}

extern "C" void kernel_launch(void* const* d_in, const int* in_sizes, int n_in,
                              void* d_out, int out_size, void* d_ws, size_t ws_size,
                              hipStream_t stream) {
    (void)in_sizes; (void)n_in; (void)d_ws; (void)ws_size; (void)out_size;
    multikr_fused<<<BTOT / SPB, 256, 0, stream>>>(
        (const int*)d_in[0],  (const int*)d_in[1],  (const float*)d_in[2],
        (const float*)d_in[3], (const float*)d_in[4], (const float*)d_in[5],
        (const float*)d_in[6], (const float*)d_in[7], (const float*)d_in[8],
        (const float*)d_in[9], (const float*)d_in[10], (const float*)d_in[11],
        (const float*)d_in[12], (const float*)d_in[13], (const float*)d_in[14],
        (const float*)d_in[15], (const float*)d_in[16], (const float*)d_in[17],
        (const float*)d_in[18], (const float*)d_in[19],
        (float*)d_out);
}